// Round 9
// baseline (105.357 us; speedup 1.0000x reference)
//
#include <hip/hip_runtime.h>
#include <hip/hip_bf16.h>
#include <math.h>

// Shapes (hard-coded by the problem)
#define B_   128
#define C1_  128
#define C2_  14
#define S_   14
#define K_   3
#define H_   256
#define E_   2

#define HT   64          // h-tile per block -> grid = 128 b * 4 groups
#define NT   4           // n-subtiles of 16
#define XROWS 224        // M padded: rows r = c2*16 + s (s<14 real, 14/15 pad)
#define XSTR 72          // xT LDS inner stride (u16): row = 144 B
#define BSTR 200         // Bt LDS inner stride (u16): row = 400 B
#define CROW 228         // Cl LDS inner stride (f32): row = 912 B

typedef unsigned short u16;
typedef unsigned int   u32;
typedef __attribute__((ext_vector_type(8))) short bf16x8;
typedef __attribute__((ext_vector_type(4))) float f32x4;

__device__ __forceinline__ u16 f2bf(float f) {  // RNE fp32->bf16
    u32 u = __float_as_uint(f);
    return (u16)((u + 0x7FFF + ((u >> 16) & 1)) >> 16);
}

__device__ __forceinline__ int decode_shift(const int* p) {
    int a = p[0];
    if (a >= -100 && a <= 100 && a != 0) return a;
    float f = __int_as_float(a);
    if (f >= -100.f && f <= 100.f && f == truncf(f) && f != 0.f) return (int)f;
    long long bits = ((long long)p[1] << 32) | (unsigned int)a;
    double d = __longlong_as_double(bits);
    if (d >= -100.0 && d <= 100.0 && d == trunc(d) && d != 0.0) return (int)d;
    return a;
}

// ---------------------------------------------------------------------------
// cvt: reformat x -> xg[b][hf][c2*16+p][c1l] bf16 (pad rows p=0,15 zeroed),
//      w1 -> wg[g][hf][hl][kk*64+c1l] bf16.  Blocks 0..255: x (one per b,hf);
//      blocks 256..263: w1.
__global__ __launch_bounds__(256) void cvt_kernel(const float* __restrict__ x,
                                                  const float* __restrict__ w1,
                                                  u16* __restrict__ xg,
                                                  u16* __restrict__ wg) {
    const int blk = blockIdx.x;
    if (blk < 256) {
        __shared__ u16 xl[64 * 200];                 // [c1l][cs], cs padded to 200
        const int b = blk >> 1, hf = blk & 1;
        const float4* src = (const float4*)(x + (size_t)(b * C1_ + hf * 64) * 196);
        for (int q = threadIdx.x; q < 12544; q += 256) {    // 64 c1 * 49 float4
            float4 v = src[q];
            int c1l = q / 49, f4 = q - c1l * 49;
            uint2 w;
            w.x = (u32)f2bf(v.x) | ((u32)f2bf(v.y) << 16);
            w.y = (u32)f2bf(v.z) | ((u32)f2bf(v.w) << 16);
            *(uint2*)&xl[c1l * 200 + f4 * 4] = w;
        }
        __syncthreads();
        u16* dst = xg + (size_t)(b * 2 + hf) * (XROWS * 64);
        for (int idx = threadIdx.x; idx < 1792; idx += 256) {  // 224 rows * 8 octs
            int row = idx >> 3, o = idx & 7;
            int c2 = row >> 4, p = row & 15;
            uint4 val = make_uint4(0, 0, 0, 0);
            if (p >= 1 && p <= 14) {
                int cs = c2 * 14 + p - 1;
                u16 v[8];
#pragma unroll
                for (int j = 0; j < 8; ++j) v[j] = xl[(o * 8 + j) * 200 + cs];
                val.x = (u32)v[0] | ((u32)v[1] << 16);
                val.y = (u32)v[2] | ((u32)v[3] << 16);
                val.z = (u32)v[4] | ((u32)v[5] << 16);
                val.w = (u32)v[6] | ((u32)v[7] << 16);
            }
            *(uint4*)&dst[idx * 8] = val;                     // coalesced
        }
    } else {
        const int base = (blk - 256) * 1536;                  // 12288 uint4 total
        for (int ii = threadIdx.x; ii < 1536; ii += 256) {
            int idx = base + ii;
            int co = idx % 24;                                // kk*8 + c1o
            int rest = idx / 24;
            int hl = rest & 63;
            int g2 = rest >> 6;                               // (g,hf)
            int hf = g2 & 1, g = g2 >> 1;
            int kk = co >> 3, c1o = co & 7;
            u16 v[8];
#pragma unroll
            for (int j = 0; j < 8; ++j) {
                int c1 = hf * 64 + c1o * 8 + j;
                v[j] = f2bf(w1[((size_t)c1 * K_ + kk) * H_ + g * 64 + hl]);
            }
            uint4 val;
            val.x = (u32)v[0] | ((u32)v[1] << 16);
            val.y = (u32)v[2] | ((u32)v[3] << 16);
            val.z = (u32)v[4] | ((u32)v[5] << 16);
            val.w = (u32)v[6] | ((u32)v[7] << 16);
            *(uint4*)&wg[(size_t)idx * 8] = val;
        }
    }
}

// ---------------------------------------------------------------------------
// Fused GEMM (16x16x32 bf16 MFMA) + in-LDS double-roll epilogue (math identical
// to R7/R8, which passed). Staging = pure uint4 copies from preformatted ws.
__global__ __launch_bounds__(256, 2) void fused_kernel(const u16* __restrict__ xg,
                                                       const float* __restrict__ w0,
                                                       const u16* __restrict__ wg,
                                                       const int* __restrict__ shift_p,
                                                       float* __restrict__ out) {
    __shared__ __align__(16) char lds[58368];
    u16*   xT = (u16*)lds;             // [226][XSTR]  (rows 224/225: overflow pad, garbage ok)
    u16*   Bt = (u16*)(lds + 32544);   // [HT][BSTR]
    float* Cl = (float*)lds;           // [HT][CROW] fp32, reused after K-loop

    const int b    = blockIdx.x >> 2;
    const int g    = blockIdx.x & 3;
    const int h0   = g * HT;
    const int t    = threadIdx.x;
    const int wave = t >> 6;
    const int lane = t & 63;
    const int quad = lane >> 4;
    const int l15  = lane & 15;

    f32x4 acc[4][NT];
#pragma unroll
    for (int i = 0; i < 4; ++i)
#pragma unroll
        for (int j = 0; j < NT; ++j) acc[i][j] = (f32x4){0.f, 0.f, 0.f, 0.f};

    for (int hf = 0; hf < 2; ++hf) {
        if (hf) __syncthreads();
        // x stage: 1792 uint4 contiguous -> LDS rows with +8 pad (conflict-free b128)
        {
            const uint4* src = (const uint4*)(xg + (size_t)(b * 2 + hf) * (XROWS * 64));
#pragma unroll
            for (int i = 0; i < 7; ++i) {
                int idx = t + 256 * i;
                uint4 v = src[idx];
                *(uint4*)&xT[(idx >> 3) * XSTR + (idx & 7) * 8] = v;
            }
        }
        // Bt stage: 1536 uint4 contiguous -> LDS rows with pad
        {
            const uint4* src = (const uint4*)(wg + (size_t)(g * 2 + hf) * (64 * 192));
#pragma unroll
            for (int i = 0; i < 6; ++i) {
                int idx = t + 256 * i;
                uint4 v = src[idx];
                int hl = idx / 24, co = idx - hl * 24;
                *(uint4*)&Bt[hl * BSTR + co * 8] = v;
            }
        }
        __syncthreads();

        // K-phase: 6 MFMA steps (kk = tt>>1, c1 half = tt&1)
#pragma unroll
        for (int tt = 0; tt < 6; ++tt) {
            const int kk = tt >> 1;
            const int coff = (tt & 1) * 32 + quad * 8;
            bf16x8 bfr[NT];
#pragma unroll
            for (int nc = 0; nc < NT; ++nc)
                bfr[nc] = *(const bf16x8*)&Bt[(nc * 16 + l15) * BSTR + kk * 64 + coff];
#pragma unroll
            for (int mi = 0; mi < 4; ++mi) {
                int mt = wave + mi * 4;
                if (mt < 14) {
                    int r = mt * 16 + l15;               // r = c2*16 + s
                    bf16x8 af = *(const bf16x8*)&xT[(r + kk) * XSTR + coff];
#pragma unroll
                    for (int nc = 0; nc < NT; ++nc)
                        acc[mi][nc] = __builtin_amdgcn_mfma_f32_16x16x32_bf16(
                            af, bfr[nc], acc[mi][nc], 0, 0, 0);
                }
            }
        }
    }

    __syncthreads();
    // C -> LDS transposed: Cl[hl][row]; f32x4 stores
#pragma unroll
    for (int mi = 0; mi < 4; ++mi) {
        int mt = wave + mi * 4;
        if (mt < 14) {
#pragma unroll
            for (int nc = 0; nc < NT; ++nc) {
                int hl = nc * 16 + l15;
                *(f32x4*)&Cl[hl * CROW + mt * 16 + quad * 4] = acc[mi][nc];
            }
        }
    }
    __syncthreads();

    // Epilogue: 2-tap roll combine (taps n-independent in ep/weight), float4 stores
    const int shift = decode_shift(shift_p);
    const int hl = t >> 2, sub = t & 3;
    const int h = h0 + hl;
    int c0[2]; float wv[2];
#pragma unroll
    for (int e = 0; e < 2; ++e) {
        int q = (e - shift) % 28; if (q < 0) q += 28;
        int np0 = q >> 1, ep = q & 1;
        int c = (np0 - shift) % 14; if (c < 0) c += 14;
        c0[e] = c;
        wv[e] = w0[h * 2 + ep];
    }
    const float* Crow = &Cl[hl * CROW];
    float* orow = out + (size_t)(b * H_ + h) * 196;
#pragma unroll
    for (int jj = 0; jj < 13; ++jj) {
        int i = sub + 4 * jj;
        if (i < 49) {
            float tmp[4];
#pragma unroll
            for (int e4 = 0; e4 < 4; ++e4) {
                int idx = 4 * i + e4;
                int n = idx / 14, m = idx - n * 14;
                int cA = c0[0] + n; if (cA >= 14) cA -= 14;
                int cB = c0[1] + n; if (cB >= 14) cB -= 14;
                tmp[e4] = wv[0] * Crow[cA * 16 + m] + wv[1] * Crow[cB * 16 + m];
            }
            *(float4*)&orow[4 * i] = make_float4(tmp[0], tmp[1], tmp[2], tmp[3]);
        }
    }
}

// ---------------------------------------------------------------------------
// Fallback (ws too small — not expected; ws measured ~268 MB): fp32 in d_out.
__global__ __launch_bounds__(256) void t4_fb(const float* __restrict__ x,
                                             const float* __restrict__ w1,
                                             float* __restrict__ t4) {
    __shared__ float xl[C1_][16];
    const int b = blockIdx.x / C2_, c2 = blockIdx.x % C2_, h = threadIdx.x;
    for (int i = h; i < C1_ * S_; i += 256) {
        int c1 = i / S_, s = i % S_;
        xl[c1][s + 1] = x[((size_t)(b * C1_ + c1) * C2_ + c2) * S_ + s];
    }
    if (h < C1_) { xl[h][0] = 0.f; xl[h][15] = 0.f; }
    __syncthreads();
    float acc[S_];
#pragma unroll
    for (int s = 0; s < S_; ++s) acc[s] = 0.f;
    for (int c1 = 0; c1 < C1_; ++c1) {
        float wa = w1[(size_t)(c1 * K_ + 0) * H_ + h];
        float wb = w1[(size_t)(c1 * K_ + 1) * H_ + h];
        float wc = w1[(size_t)(c1 * K_ + 2) * H_ + h];
#pragma unroll
        for (int s = 0; s < S_; ++s)
            acc[s] += wa * xl[c1][s] + wb * xl[c1][s + 1] + wc * xl[c1][s + 2];
    }
    size_t base = ((size_t)(b * H_ + h) * C2_ + c2) * S_;
#pragma unroll
    for (int s = 0; s < S_; ++s) t4[base + s] = acc[s];
}
__global__ __launch_bounds__(224) void out_fb(float* __restrict__ t4,
                                              const float* __restrict__ w0,
                                              const int* __restrict__ shift_p) {
    const int tid = threadIdx.x;
    const int m = tid % S_, hh = tid / S_;
    const int b = blockIdx.x / 16, h = (blockIdx.x % 16) * 16 + hh;
    const int shift = decode_shift(shift_p);
    const size_t colbase = ((size_t)(b * H_ + h) * C2_) * S_ + m;
    float tl[C2_];
#pragma unroll
    for (int c2 = 0; c2 < C2_; ++c2) tl[c2] = t4[colbase + (size_t)c2 * S_];
    const float w0v[2] = { w0[h * 2 + 0], w0[h * 2 + 1] };
    float r[C2_];
#pragma unroll
    for (int n = 0; n < C2_; ++n) {
        float a = 0.f;
#pragma unroll
        for (int e = 0; e < 2; ++e) {
            int q = (2 * n + e - shift) % 28; if (q < 0) q += 28;
            int np = q >> 1, ep = q & 1;
            int c2 = (np - shift) % 14; if (c2 < 0) c2 += 14;
            a += tl[c2] * w0v[ep];
        }
        r[n] = a;
    }
#pragma unroll
    for (int n = 0; n < C2_; ++n) t4[colbase + (size_t)n * S_] = r[n];
}

extern "C" void kernel_launch(void* const* d_in, const int* in_sizes, int n_in,
                              void* d_out, int out_size, void* d_ws, size_t ws_size,
                              hipStream_t stream) {
    const float* x     = (const float*)d_in[0];
    const float* w0    = (const float*)d_in[1];
    const float* w1    = (const float*)d_in[2];
    const int*   shift = (const int*)(n_in > 3 ? d_in[3] : d_in[n_in - 1]);
    for (int i = 0; i < n_in; ++i) {
        int sz = in_sizes[i];
        if (sz == B_ * C1_ * C2_ * S_)      x     = (const float*)d_in[i];
        else if (sz == H_ * E_)             w0    = (const float*)d_in[i];
        else if (sz == C1_ * K_ * H_)       w1    = (const float*)d_in[i];
        else if (sz == 1)                   shift = (const int*)d_in[i];
    }
    float* out = (float*)d_out;

    const size_t NXG = (size_t)B_ * 2 * XROWS * 64;   // 3,670,016 u16
    const size_t NWG = (size_t)4 * 2 * 64 * 192;      //    98,304 u16
    if (ws_size >= (NXG + NWG) * sizeof(u16)) {
        u16* xg = (u16*)d_ws;
        u16* wg = xg + NXG;
        cvt_kernel<<<264, 256, 0, stream>>>(x, w1, xg, wg);
        fused_kernel<<<B_ * 4, 256, 0, stream>>>(xg, w0, wg, shift, out);
    } else {
        t4_fb<<<B_ * C2_, 256, 0, stream>>>(x, w1, out);
        out_fb<<<B_ * 16, 224, 0, stream>>>(out, w0, shift);
    }
}

// Round 10
// 89.911 us; speedup vs baseline: 1.1718x; 1.1718x over previous
//
#include <hip/hip_runtime.h>
#include <hip/hip_bf16.h>
#include <math.h>

// Shapes (hard-coded by the problem)
#define B_   128
#define C1_  128
#define C2_  14
#define S_   14
#define K_   3
#define H_   256
#define E_   2

#define HT   64          // h-tile per block -> grid = 128 b * 4 groups
#define NT   4           // n-subtiles of 16
#define XROWS 224        // M padded: rows r = c2*16 + p (p=s+1; p=0,15 zero pads)
#define XSTR 72          // xT LDS inner stride (u16): row = 144 B
#define BSTR 200         // Bt LDS inner stride (u16): row = 400 B
#define CROW 228         // Cl LDS inner stride (f32): row = 912 B

typedef unsigned short u16;
typedef unsigned int   u32;
typedef __attribute__((ext_vector_type(8))) short bf16x8;
typedef __attribute__((ext_vector_type(4))) float f32x4;

__device__ __forceinline__ u16 f2bf(float f) {  // RNE fp32->bf16
    u32 u = __float_as_uint(f);
    return (u16)((u + 0x7FFF + ((u >> 16) & 1)) >> 16);
}

__device__ __forceinline__ int decode_shift(const int* p) {
    int a = p[0];
    if (a >= -100 && a <= 100 && a != 0) return a;
    float f = __int_as_float(a);
    if (f >= -100.f && f <= 100.f && f == truncf(f) && f != 0.f) return (int)f;
    long long bits = ((long long)p[1] << 32) | (unsigned int)a;
    double d = __longlong_as_double(bits);
    if (d >= -100.0 && d <= 100.0 && d == trunc(d) && d != 0.0) return (int)d;
    return a;
}

// ---------------------------------------------------------------------------
// cvt: x -> xg[b][hf][row=c2*16+p][c1l(64)] bf16 (pad rows zeroed),
//      w1 -> wg[g][hf][hl][kk*64+c1l] bf16.
// Blocks 0..1023: x, one per (b, hf, row-quarter). Each 56-row quarter maps to
// exactly 49 contiguous cs -> coalesced f32 reads, LDS transpose, uint4 writes.
// Blocks 1024..1119: w1, one float4 coalesced read per thread.
__global__ __launch_bounds__(256) void cvt_kernel(const float* __restrict__ x,
                                                  const float* __restrict__ w1,
                                                  u16* __restrict__ xg,
                                                  u16* __restrict__ wg) {
    const int blk = blockIdx.x;
    const int t   = threadIdx.x;
    if (blk < 1024) {
        __shared__ u16 xl[64 * 50];                  // [c1l][csl], stride 50
        const int b   = blk >> 3;
        const int hf  = (blk >> 2) & 1;
        const int qr  = blk & 3;
        const int cs0 = qr * 49;
        const float* xb = x + (size_t)(b * C1_ + hf * 64) * 196 + cs0;
#pragma unroll
        for (int i = 0; i < 13; ++i) {               // 64 c1 * 49 cs = 3136 loads
            int idx = t + 256 * i;
            if (idx < 3136) {
                int c1l = idx / 49, j = idx - c1l * 49;
                xl[c1l * 50 + j] = f2bf(xb[c1l * 196 + j]);
            }
        }
        __syncthreads();
        u16* dst = xg + ((size_t)(b * 2 + hf) * XROWS + qr * 56) * 64;
#pragma unroll
        for (int i = 0; i < 2; ++i) {                // 56 rows * 8 octs = 448 tasks
            int task = t + 256 * i;
            if (task < 448) {
                int rr = task >> 3, o = task & 7;
                int row = qr * 56 + rr;
                int p = row & 15;
                uint4 val = make_uint4(0, 0, 0, 0);
                if (p >= 1 && p <= 14) {
                    int csl = (row >> 4) * 14 + p - 1 - cs0;   // in [0,48]
                    u16 v[8];
#pragma unroll
                    for (int j = 0; j < 8; ++j) v[j] = xl[(o * 8 + j) * 50 + csl];
                    val.x = (u32)v[0] | ((u32)v[1] << 16);
                    val.y = (u32)v[2] | ((u32)v[3] << 16);
                    val.z = (u32)v[4] | ((u32)v[5] << 16);
                    val.w = (u32)v[6] | ((u32)v[7] << 16);
                }
                *(uint4*)&dst[(size_t)rr * 64 + o * 8] = val;   // coalesced
            }
        }
    } else {
        int q = (blk - 1024) * 256 + t;              // [0, 24576) float4s of w1
        float4 v = ((const float4*)w1)[q];
        int i0 = q * 4;
        int c1 = i0 / 768;
        int kk = (i0 - c1 * 768) >> 8;
        int h0 = i0 & 255;
        int hf = c1 >> 6, c1l = c1 & 63;
        u16 b4[4] = { f2bf(v.x), f2bf(v.y), f2bf(v.z), f2bf(v.w) };
#pragma unroll
        for (int d = 0; d < 4; ++d) {
            int h = h0 + d, g = h >> 6, hl = h & 63;
            wg[(size_t)((g * 2 + hf) * 64 + hl) * 192 + kk * 64 + c1l] = b4[d];
        }
    }
}

// ---------------------------------------------------------------------------
// Fused GEMM (16x16x32 bf16 MFMA) + in-LDS double-roll epilogue — byte-identical
// to R9 (passed). Staging = pure uint4 copies from preformatted ws.
__global__ __launch_bounds__(256, 2) void fused_kernel(const u16* __restrict__ xg,
                                                       const float* __restrict__ w0,
                                                       const u16* __restrict__ wg,
                                                       const int* __restrict__ shift_p,
                                                       float* __restrict__ out) {
    __shared__ __align__(16) char lds[58368];
    u16*   xT = (u16*)lds;             // [226][XSTR]
    u16*   Bt = (u16*)(lds + 32544);   // [HT][BSTR]
    float* Cl = (float*)lds;           // [HT][CROW] fp32, reused after K-loop

    const int b    = blockIdx.x >> 2;
    const int g    = blockIdx.x & 3;
    const int h0   = g * HT;
    const int t    = threadIdx.x;
    const int wave = t >> 6;
    const int lane = t & 63;
    const int quad = lane >> 4;
    const int l15  = lane & 15;

    f32x4 acc[4][NT];
#pragma unroll
    for (int i = 0; i < 4; ++i)
#pragma unroll
        for (int j = 0; j < NT; ++j) acc[i][j] = (f32x4){0.f, 0.f, 0.f, 0.f};

    for (int hf = 0; hf < 2; ++hf) {
        if (hf) __syncthreads();
        {
            const uint4* src = (const uint4*)(xg + (size_t)(b * 2 + hf) * (XROWS * 64));
#pragma unroll
            for (int i = 0; i < 7; ++i) {
                int idx = t + 256 * i;
                uint4 v = src[idx];
                *(uint4*)&xT[(idx >> 3) * XSTR + (idx & 7) * 8] = v;
            }
        }
        {
            const uint4* src = (const uint4*)(wg + (size_t)(g * 2 + hf) * (64 * 192));
#pragma unroll
            for (int i = 0; i < 6; ++i) {
                int idx = t + 256 * i;
                uint4 v = src[idx];
                int hl = idx / 24, co = idx - hl * 24;
                *(uint4*)&Bt[hl * BSTR + co * 8] = v;
            }
        }
        __syncthreads();

#pragma unroll
        for (int tt = 0; tt < 6; ++tt) {
            const int kk = tt >> 1;
            const int coff = (tt & 1) * 32 + quad * 8;
            bf16x8 bfr[NT];
#pragma unroll
            for (int nc = 0; nc < NT; ++nc)
                bfr[nc] = *(const bf16x8*)&Bt[(nc * 16 + l15) * BSTR + kk * 64 + coff];
#pragma unroll
            for (int mi = 0; mi < 4; ++mi) {
                int mt = wave + mi * 4;
                if (mt < 14) {
                    int r = mt * 16 + l15;               // r = c2*16 + s
                    bf16x8 af = *(const bf16x8*)&xT[(r + kk) * XSTR + coff];
#pragma unroll
                    for (int nc = 0; nc < NT; ++nc)
                        acc[mi][nc] = __builtin_amdgcn_mfma_f32_16x16x32_bf16(
                            af, bfr[nc], acc[mi][nc], 0, 0, 0);
                }
            }
        }
    }

    __syncthreads();
#pragma unroll
    for (int mi = 0; mi < 4; ++mi) {
        int mt = wave + mi * 4;
        if (mt < 14) {
#pragma unroll
            for (int nc = 0; nc < NT; ++nc) {
                int hl = nc * 16 + l15;
                *(f32x4*)&Cl[hl * CROW + mt * 16 + quad * 4] = acc[mi][nc];
            }
        }
    }
    __syncthreads();

    const int shift = decode_shift(shift_p);
    const int hl = t >> 2, sub = t & 3;
    const int h = h0 + hl;
    int c0[2]; float wv[2];
#pragma unroll
    for (int e = 0; e < 2; ++e) {
        int q = (e - shift) % 28; if (q < 0) q += 28;
        int np0 = q >> 1, ep = q & 1;
        int c = (np0 - shift) % 14; if (c < 0) c += 14;
        c0[e] = c;
        wv[e] = w0[h * 2 + ep];
    }
    const float* Crow = &Cl[hl * CROW];
    float* orow = out + (size_t)(b * H_ + h) * 196;
#pragma unroll
    for (int jj = 0; jj < 13; ++jj) {
        int i = sub + 4 * jj;
        if (i < 49) {
            float tmp[4];
#pragma unroll
            for (int e4 = 0; e4 < 4; ++e4) {
                int idx = 4 * i + e4;
                int n = idx / 14, m = idx - n * 14;
                int cA = c0[0] + n; if (cA >= 14) cA -= 14;
                int cB = c0[1] + n; if (cB >= 14) cB -= 14;
                tmp[e4] = wv[0] * Crow[cA * 16 + m] + wv[1] * Crow[cB * 16 + m];
            }
            *(float4*)&orow[4 * i] = make_float4(tmp[0], tmp[1], tmp[2], tmp[3]);
        }
    }
}

// ---------------------------------------------------------------------------
// Fallback (ws too small — not expected; ws measured ~268 MB).
__global__ __launch_bounds__(256) void t4_fb(const float* __restrict__ x,
                                             const float* __restrict__ w1,
                                             float* __restrict__ t4) {
    __shared__ float xl[C1_][16];
    const int b = blockIdx.x / C2_, c2 = blockIdx.x % C2_, h = threadIdx.x;
    for (int i = h; i < C1_ * S_; i += 256) {
        int c1 = i / S_, s = i % S_;
        xl[c1][s + 1] = x[((size_t)(b * C1_ + c1) * C2_ + c2) * S_ + s];
    }
    if (h < C1_) { xl[h][0] = 0.f; xl[h][15] = 0.f; }
    __syncthreads();
    float acc[S_];
#pragma unroll
    for (int s = 0; s < S_; ++s) acc[s] = 0.f;
    for (int c1 = 0; c1 < C1_; ++c1) {
        float wa = w1[(size_t)(c1 * K_ + 0) * H_ + h];
        float wb = w1[(size_t)(c1 * K_ + 1) * H_ + h];
        float wc = w1[(size_t)(c1 * K_ + 2) * H_ + h];
#pragma unroll
        for (int s = 0; s < S_; ++s)
            acc[s] += wa * xl[c1][s] + wb * xl[c1][s + 1] + wc * xl[c1][s + 2];
    }
    size_t base = ((size_t)(b * H_ + h) * C2_ + c2) * S_;
#pragma unroll
    for (int s = 0; s < S_; ++s) t4[base + s] = acc[s];
}
__global__ __launch_bounds__(224) void out_fb(float* __restrict__ t4,
                                              const float* __restrict__ w0,
                                              const int* __restrict__ shift_p) {
    const int tid = threadIdx.x;
    const int m = tid % S_, hh = tid / S_;
    const int b = blockIdx.x / 16, h = (blockIdx.x % 16) * 16 + hh;
    const int shift = decode_shift(shift_p);
    const size_t colbase = ((size_t)(b * H_ + h) * C2_) * S_ + m;
    float tl[C2_];
#pragma unroll
    for (int c2 = 0; c2 < C2_; ++c2) tl[c2] = t4[colbase + (size_t)c2 * S_];
    const float w0v[2] = { w0[h * 2 + 0], w0[h * 2 + 1] };
    float r[C2_];
#pragma unroll
    for (int n = 0; n < C2_; ++n) {
        float a = 0.f;
#pragma unroll
        for (int e = 0; e < 2; ++e) {
            int q = (2 * n + e - shift) % 28; if (q < 0) q += 28;
            int np = q >> 1, ep = q & 1;
            int c2 = (np - shift) % 14; if (c2 < 0) c2 += 14;
            a += tl[c2] * w0v[ep];
        }
        r[n] = a;
    }
#pragma unroll
    for (int n = 0; n < C2_; ++n) t4[colbase + (size_t)n * S_] = r[n];
}

extern "C" void kernel_launch(void* const* d_in, const int* in_sizes, int n_in,
                              void* d_out, int out_size, void* d_ws, size_t ws_size,
                              hipStream_t stream) {
    const float* x     = (const float*)d_in[0];
    const float* w0    = (const float*)d_in[1];
    const float* w1    = (const float*)d_in[2];
    const int*   shift = (const int*)(n_in > 3 ? d_in[3] : d_in[n_in - 1]);
    for (int i = 0; i < n_in; ++i) {
        int sz = in_sizes[i];
        if (sz == B_ * C1_ * C2_ * S_)      x     = (const float*)d_in[i];
        else if (sz == H_ * E_)             w0    = (const float*)d_in[i];
        else if (sz == C1_ * K_ * H_)       w1    = (const float*)d_in[i];
        else if (sz == 1)                   shift = (const int*)d_in[i];
    }
    float* out = (float*)d_out;

    const size_t NXG = (size_t)B_ * 2 * XROWS * 64;   // 3,670,016 u16
    const size_t NWG = (size_t)4 * 2 * 64 * 192;      //    98,304 u16
    if (ws_size >= (NXG + NWG) * sizeof(u16)) {
        u16* xg = (u16*)d_ws;
        u16* wg = xg + NXG;
        cvt_kernel<<<1024 + 96, 256, 0, stream>>>(x, w1, xg, wg);
        fused_kernel<<<B_ * 4, 256, 0, stream>>>(xg, w0, wg, shift, out);
    } else {
        t4_fb<<<B_ * C2_, 256, 0, stream>>>(x, w1, out);
        out_fb<<<B_ * 16, 224, 0, stream>>>(out, w0, shift);
    }
}